// Round 2
// baseline (122.697 us; speedup 1.0000x reference)
//
#include <hip/hip_runtime.h>
#include <cmath>

typedef float f32x4 __attribute__((ext_vector_type(4)));
typedef __bf16 bfx8 __attribute__((ext_vector_type(8)));
typedef const __attribute__((address_space(1))) void g_void;
typedef __attribute__((address_space(3))) void lds_void;

#define B_SZ 32
#define CIN 256
#define HW 32
#define OUTC 256
#define KTOT 2304
#define HP 34
#define M_TOT 32768

// ---- ws layout (bytes) ----
#define XP_OFF   0u
#define XP_BYTES 18939904u          // 32*34*34*256 * 2  (FIXED: was 18935808, 4KB short -> Wt overlapped xp padding)
#define WT_OFF   (XP_OFF + XP_BYTES)
#define WT_BYTES 1179648u           // 2304*256 * 2
#define ZN_OFF   (WT_OFF + WT_BYTES)
#define MF_OFF   (ZN_OFF + 1024u)
#define T_OFF    (MF_OFF + 262144u)
// total ~19.6 MB

__device__ __forceinline__ unsigned short f2bf(float f) {
  union { float f; unsigned u; } v; v.f = f;
  unsigned r = v.u + 0x7FFFu + ((v.u >> 16) & 1u);
  return (unsigned short)(r >> 16);
}

__device__ __forceinline__ void gload16(const void* g, void* l) {
  __builtin_amdgcn_global_load_lds((g_void*)g, (lds_void*)l, 16, 0, 0);
}

__device__ __forceinline__ float asinh_f(float x) { return logf(x + sqrtf(x * x + 1.f)); }
__device__ __forceinline__ float sinh_f(float v)  { float e = expf(v); return 0.5f * (e - 1.f / e); }
__device__ __forceinline__ float atanh_f(float t) { return 0.5f * logf((1.f + t) / (1.f - t)); }

// ---- prep: scaled bf16 channel-last padded image + per-pixel channel sumsq ----
__global__ void k_prep_x(const float* __restrict__ x, unsigned short* __restrict__ xp,
                         float* __restrict__ T, float ratio) {
  __shared__ float tile[256][33];
  __shared__ float red[8][32];
  const int h = blockIdx.x, b = blockIdx.y, t = threadIdx.x;
  const int w = t & 31, g = t >> 5;
  const float* xb = x + ((b * 256) * 32 + h) * 32;
#pragma unroll
  for (int i = 0; i < 32; ++i) {
    int c = i * 8 + g;
    tile[c][w] = xb[c * 1024 + w] * ratio;
  }
  __syncthreads();
  unsigned short* xpb = xp + ((b * HP + h + 1) * HP + 1) * 256 + t;
#pragma unroll 8
  for (int w2 = 0; w2 < 32; ++w2) xpb[w2 * 256] = f2bf(tile[t][w2]);
  float s = 0.f;
#pragma unroll
  for (int j = 0; j < 32; ++j) { float v = tile[g * 32 + j][w]; s += v * v; }
  red[g][w] = s;
  __syncthreads();
  if (t < 32) {
    float a = 0.f;
#pragma unroll
    for (int q = 0; q < 8; ++q) a += red[q][t];
    T[(b * 32 + h) * 32 + t] = a;
  }
}

// ---- per-row factors: (lam*hfac, lam-1) ----
__global__ void k_rowfac(const float* __restrict__ T, float2* __restrict__ mf) {
  int m = blockIdx.x * 256 + threadIdx.x;
  int b = m >> 10, ohw = m & 1023, oh = ohw >> 5, ow = ohw & 31;
  const float* Tb = T + b * 1024;
  float nv2 = 0.f;
  for (int di = -1; di <= 1; ++di) {
    int hh = oh + di; if (hh < 0 || hh > 31) continue;
    for (int dj = -1; dj <= 1; ++dj) {
      int ww = ow + dj; if (ww < 0 || ww > 31) continue;
      nv2 += Tb[hh * 32 + ww];
    }
  }
  float n = sqrtf(fmaxf(nv2, 1e-30f));
  float th = tanhf(n);
  float hf = th / n;
  float lam = 2.f / fmaxf(1.f - th * th, 1e-12f);
  mf[m] = make_float2(lam * hf, lam - 1.f);
}

// ---- column norms of weights (deterministic tree reduce) ----
__global__ void k_zn(const float* __restrict__ wts, float* __restrict__ zn2) {
  __shared__ float red[256];
  int o = blockIdx.x, t = threadIdx.x;
  float a = 0.f;
#pragma unroll
  for (int j = 0; j < 9; ++j) { float v = wts[(t + j * 256) * 256 + o]; a += v * v; }
  red[t] = a; __syncthreads();
  for (int s = 128; s > 0; s >>= 1) { if (t < s) red[t] += red[t + s]; __syncthreads(); }
  if (t == 0) zn2[o] = red[0];
}

// ---- normalized transposed weights, k' = patch*256 + c ----
__global__ void k_wt(const float* __restrict__ wts, const float* __restrict__ zn2,
                     unsigned short* __restrict__ Wt) {
  int d = blockIdx.x, o = threadIdx.x;
  float zn = sqrtf(fmaxf(zn2[o], 1e-30f));
  float v = wts[d * 256 + o] / zn;
  int c = d / 9, kk = d - c * 9;
  Wt[o * KTOT + kk * 256 + c] = f2bf(v);
}

// ---- main fused GEMM + hyperbolic epilogue ----
__global__ __launch_bounds__(512) void k_gemm(
    const unsigned short* __restrict__ xp, const unsigned short* __restrict__ Wt,
    const float* __restrict__ zn2, const float* __restrict__ bias,
    const float2* __restrict__ mf, float* __restrict__ out) {
  __shared__ __align__(16) unsigned short As[2][256 * 32];  // weights tile [256 o][32 k]
  __shared__ __align__(16) unsigned short Bs[2][128 * 32];  // image tile  [128 m][32 k]
  __shared__ float zn_s[256], C_s[256], S_s[256];
  __shared__ float2 mf_s[128];
  __shared__ float part_s[4][128];

  const int tid = threadIdx.x;
  const int wid = tid >> 6, lane = tid & 63;
  const int m0 = blockIdx.x * 128;
  const int b = m0 >> 10, ohw0 = m0 & 1023;

  // stage epilogue tables (wave-aligned branches)
  if (tid < 128) {
    mf_s[tid] = mf[m0 + tid];
  } else if (tid < 384) {
    int o = tid - 128;
    float zn = sqrtf(fmaxf(zn2[o], 1e-30f));
    float e = expf(2.f * bias[o]);
    float ie = 1.f / e;
    zn_s[o] = zn;
    C_s[o] = 0.5f * (e + ie);
    S_s[o] = 0.5f * (e - ie);
  }

  // per-thread staging addresses
  const int ml = tid >> 2, cp = tid & 3;
  const int oh = (ohw0 + ml) >> 5, ow = (ohw0 + ml) & 31;
  const unsigned short* src_img_base = xp + ((b * HP + oh) * HP + ow) * 256 + cp * 8;
  const unsigned short* src_w1 = Wt + (tid >> 2) * KTOT + (tid & 3) * 8;
  const unsigned short* src_w2 = src_w1 + 128 * KTOT;

  f32x4 acc[4][4];
#pragma unroll
  for (int i = 0; i < 4; ++i)
#pragma unroll
    for (int j = 0; j < 4; ++j) acc[i][j] = f32x4{0.f, 0.f, 0.f, 0.f};

  auto stage = [&](int buf, int t) {
    int kk = t >> 3, c0 = (t & 7) << 5;
    int di = (kk >= 6) ? 2 : ((kk >= 3) ? 1 : 0);
    int dj = kk - di * 3;
    gload16(src_img_base + (di * HP + dj) * 256 + c0, (char*)&Bs[buf][0] + wid * 1024);
    gload16(src_w1 + t * 32, (char*)&As[buf][0] + wid * 1024);
    gload16(src_w2 + t * 32, (char*)&As[buf][0] + 8192 + wid * 1024);
  };

  stage(0, 0);
  __syncthreads();

  const int kq = lane >> 4, l15 = lane & 15;
  const int o_base = (wid >> 1) * 64, m_base = (wid & 1) * 64;

  int cur = 0;
  for (int t = 0; t < 72; ++t) {
    if (t < 71) stage(cur ^ 1, t + 1);
    const bfx8* Ap = (const bfx8*)&As[cur][0];
    const bfx8* Bp = (const bfx8*)&Bs[cur][0];
    bfx8 fa[4], fb[4];
#pragma unroll
    for (int oi = 0; oi < 4; ++oi) fa[oi] = Ap[(o_base + oi * 16 + l15) * 4 + kq];
#pragma unroll
    for (int mi = 0; mi < 4; ++mi) fb[mi] = Bp[(m_base + mi * 16 + l15) * 4 + kq];
#pragma unroll
    for (int oi = 0; oi < 4; ++oi)
#pragma unroll
      for (int mi = 0; mi < 4; ++mi)
        acc[oi][mi] = __builtin_amdgcn_mfma_f32_16x16x32_bf16(fa[oi], fb[mi], acc[oi][mi], 0, 0, 0);
    __syncthreads();
    cur ^= 1;
  }

  // ---- epilogue: w = sinh(2 zn asinh(Am*dot*C - Bm*S)) ----
#pragma unroll
  for (int oi = 0; oi < 4; ++oi) {
#pragma unroll
    for (int r = 0; r < 4; ++r) {
      int o = o_base + oi * 16 + kq * 4 + r;
      float zn2o = 2.f * zn_s[o], Co = C_s[o], So = S_s[o];
#pragma unroll
      for (int mi = 0; mi < 4; ++mi) {
        int mloc = m_base + mi * 16 + l15;
        float2 f = mf_s[mloc];
        float arg = f.x * acc[oi][mi][r] * Co - f.y * So;
        acc[oi][mi][r] = sinh_f(zn2o * asinh_f(arg));
      }
    }
  }

  // row sums of w^2 over o (256 = 4 wave-groups x 64)
  float swp[4];
#pragma unroll
  for (int mi = 0; mi < 4; ++mi) {
    float s = 0.f;
#pragma unroll
    for (int oi = 0; oi < 4; ++oi)
#pragma unroll
      for (int r = 0; r < 4; ++r) s += acc[oi][mi][r] * acc[oi][mi][r];
    s += __shfl_xor(s, 16);
    s += __shfl_xor(s, 32);
    swp[mi] = s;
  }
  if (lane < 16) {
#pragma unroll
    for (int mi = 0; mi < 4; ++mi) part_s[wid >> 1][m_base + mi * 16 + lane] = swp[mi];
  }
  __syncthreads();

  float gm[4];
#pragma unroll
  for (int mi = 0; mi < 4; ++mi) {
    int mloc = m_base + mi * 16 + l15;
    float Sw = part_s[0][mloc] + part_s[1][mloc] + part_s[2][mloc] + part_s[3][mloc];
    float sq = sqrtf(fmaxf(Sw, 1e-30f));
    float s = 1.f / (1.f + sqrtf(1.f + Sw));
    float tt = fminf(s * sq, 1.f - 1e-7f);
    gm[mi] = atanh_f(tt) / sq;
  }

  float* outb = out + (b * 256) * 1024 + ohw0;
#pragma unroll
  for (int oi = 0; oi < 4; ++oi) {
#pragma unroll
    for (int r = 0; r < 4; ++r) {
      int o = o_base + oi * 16 + kq * 4 + r;
      float* op = outb + o * 1024;
#pragma unroll
      for (int mi = 0; mi < 4; ++mi)
        op[m_base + mi * 16 + l15] = acc[oi][mi][r] * gm[mi];
    }
  }
}

extern "C" void kernel_launch(void* const* d_in, const int* in_sizes, int n_in,
                              void* d_out, int out_size, void* d_ws, size_t ws_size,
                              hipStream_t stream) {
  const float* x    = (const float*)d_in[0];
  const float* wts  = (const float*)d_in[1];
  const float* bias = (const float*)d_in[2];
  float* out = (float*)d_out;
  char* ws = (char*)d_ws;
  unsigned short* xp = (unsigned short*)(ws + XP_OFF);
  unsigned short* Wt = (unsigned short*)(ws + WT_OFF);
  float* zn2 = (float*)(ws + ZN_OFF);
  float2* mfv = (float2*)(ws + MF_OFF);
  float* T = (float*)(ws + T_OFF);

  double bni = exp(::lgamma(128.0) + ::lgamma(0.5) - ::lgamma(128.5));
  double bn  = exp(::lgamma(1152.0) + ::lgamma(0.5) - ::lgamma(1152.5));
  float ratio = (float)(bn / bni);

  hipMemsetAsync(xp, 0, XP_BYTES, stream);
  k_prep_x<<<dim3(32, 32), 256, 0, stream>>>(x, xp, T, ratio);
  k_rowfac<<<128, 256, 0, stream>>>(T, mfv);
  k_zn<<<256, 256, 0, stream>>>(wts, zn2);
  k_wt<<<KTOT, 256, 0, stream>>>(wts, zn2, Wt);
  k_gemm<<<256, 512, 0, stream>>>(xp, Wt, zn2, bias, mfv, out);
}

// Round 3
// 94.200 us; speedup vs baseline: 1.3025x; 1.3025x over previous
//
#include <hip/hip_runtime.h>
#include <cmath>

typedef float f32x4 __attribute__((ext_vector_type(4)));
typedef __bf16 bfx8 __attribute__((ext_vector_type(8)));
typedef const __attribute__((address_space(1))) void g_void;
typedef __attribute__((address_space(3))) void lds_void;

#define B_SZ 32
#define CIN 256
#define HW 32
#define OUTC 256
#define KTOT 2304
#define HP 34
#define M_TOT 32768

// ---- ws layout (bytes) ----
#define XP_OFF   0u
#define XP_BYTES 18939904u          // 32*34*34*256 * 2
#define WT_OFF   (XP_OFF + XP_BYTES)
#define WT_BYTES 1179648u           // 2304*256 * 2
#define ZN_OFF   (WT_OFF + WT_BYTES)
#define MF_OFF   (ZN_OFF + 1024u)
#define T_OFF    (MF_OFF + 262144u)

// ---- dynamic LDS layout for k_gemm (bytes) ----
// A[2]: 2 x 256x64 bf16 = 65536 ; B[2]: 2 x 128x64 bf16 = 32768 ; tables 6144
#define LDS_A_OFF 0
#define LDS_B_OFF 65536
#define LDS_TAB   98304
#define LDS_TOTAL 104448

__device__ __forceinline__ unsigned short f2bf(float f) {
  union { float f; unsigned u; } v; v.f = f;
  unsigned r = v.u + 0x7FFFu + ((v.u >> 16) & 1u);
  return (unsigned short)(r >> 16);
}

__device__ __forceinline__ void gload16(const void* g, void* l) {
  __builtin_amdgcn_global_load_lds((g_void*)g, (lds_void*)l, 16, 0, 0);
}

__device__ __forceinline__ float asinh_f(float x) { return logf(x + sqrtf(x * x + 1.f)); }
__device__ __forceinline__ float sinh_f(float v)  { float e = expf(v); return 0.5f * (e - 1.f / e); }
__device__ __forceinline__ float atanh_f(float t) { return 0.5f * logf((1.f + t) / (1.f - t)); }

#define MEMBAR() asm volatile("" ::: "memory")
#define RAWBAR() do { MEMBAR(); __builtin_amdgcn_s_barrier(); MEMBAR(); } while (0)

// ---- prep: scaled bf16 channel-last padded image + per-pixel channel sumsq ----
__global__ void k_prep_x(const float* __restrict__ x, unsigned short* __restrict__ xp,
                         float* __restrict__ T, float ratio) {
  __shared__ float tile[256][33];
  __shared__ float red[8][32];
  const int h = blockIdx.x, b = blockIdx.y, t = threadIdx.x;
  const int w = t & 31, g = t >> 5;
  const float* xb = x + ((b * 256) * 32 + h) * 32;
#pragma unroll
  for (int i = 0; i < 32; ++i) {
    int c = i * 8 + g;
    tile[c][w] = xb[c * 1024 + w] * ratio;
  }
  __syncthreads();
  unsigned short* xpb = xp + ((b * HP + h + 1) * HP + 1) * 256 + t;
#pragma unroll 8
  for (int w2 = 0; w2 < 32; ++w2) xpb[w2 * 256] = f2bf(tile[t][w2]);
  float s = 0.f;
#pragma unroll
  for (int j = 0; j < 32; ++j) { float v = tile[g * 32 + j][w]; s += v * v; }
  red[g][w] = s;
  __syncthreads();
  if (t < 32) {
    float a = 0.f;
#pragma unroll
    for (int q = 0; q < 8; ++q) a += red[q][t];
    T[(b * 32 + h) * 32 + t] = a;
  }
}

// ---- per-row factors: (lam*hfac, lam-1) ----
__global__ void k_rowfac(const float* __restrict__ T, float2* __restrict__ mf) {
  int m = blockIdx.x * 256 + threadIdx.x;
  int b = m >> 10, ohw = m & 1023, oh = ohw >> 5, ow = ohw & 31;
  const float* Tb = T + b * 1024;
  float nv2 = 0.f;
  for (int di = -1; di <= 1; ++di) {
    int hh = oh + di; if (hh < 0 || hh > 31) continue;
    for (int dj = -1; dj <= 1; ++dj) {
      int ww = ow + dj; if (ww < 0 || ww > 31) continue;
      nv2 += Tb[hh * 32 + ww];
    }
  }
  float n = sqrtf(fmaxf(nv2, 1e-30f));
  float th = tanhf(n);
  float hf = th / n;
  float lam = 2.f / fmaxf(1.f - th * th, 1e-12f);
  mf[m] = make_float2(lam * hf, lam - 1.f);
}

// ---- column norms of weights (deterministic tree reduce) ----
__global__ void k_zn(const float* __restrict__ wts, float* __restrict__ zn2) {
  __shared__ float red[256];
  int o = blockIdx.x, t = threadIdx.x;
  float a = 0.f;
#pragma unroll
  for (int j = 0; j < 9; ++j) { float v = wts[(t + j * 256) * 256 + o]; a += v * v; }
  red[t] = a; __syncthreads();
  for (int s = 128; s > 0; s >>= 1) { if (t < s) red[t] += red[t + s]; __syncthreads(); }
  if (t == 0) zn2[o] = red[0];
}

// ---- normalized transposed weights, k' = patch*256 + c ----
__global__ void k_wt(const float* __restrict__ wts, const float* __restrict__ zn2,
                     unsigned short* __restrict__ Wt) {
  int d = blockIdx.x, o = threadIdx.x;
  float zn = sqrtf(fmaxf(zn2[o], 1e-30f));
  float v = wts[d * 256 + o] / zn;
  int c = d / 9, kk = d - c * 9;
  Wt[o * KTOT + kk * 256 + c] = f2bf(v);
}

// ---- main fused GEMM + hyperbolic epilogue (counted-vmcnt ring-2 pipeline) ----
__global__ __launch_bounds__(512, 2) void k_gemm(
    const unsigned short* __restrict__ xp, const unsigned short* __restrict__ Wt,
    const float* __restrict__ zn2, const float* __restrict__ bias,
    const float2* __restrict__ mf, float* __restrict__ out) {
  extern __shared__ char smem[];

  const int tid = threadIdx.x;
  const int wid = tid >> 6, lane = tid & 63;
  const int m0 = blockIdx.x * 128;
  const int b = m0 >> 10, ohw0 = m0 & 1023;

  float2* mf_s = (float2*)(smem + LDS_TAB);
  float* zn_s = (float*)(smem + LDS_TAB + 1024);
  float* C_s  = (float*)(smem + LDS_TAB + 2048);
  float* S_s  = (float*)(smem + LDS_TAB + 3072);
  float (*part_s)[128] = (float (*)[128])(smem + LDS_TAB + 4096);

  // stage epilogue tables (wave-aligned branches)
  if (tid < 128) {
    mf_s[tid] = mf[m0 + tid];
  } else if (tid < 384) {
    int o = tid - 128;
    float zn = sqrtf(fmaxf(zn2[o], 1e-30f));
    float e = expf(2.f * bias[o]);
    float ie = 1.f / e;
    zn_s[o] = zn;
    C_s[o] = 0.5f * (e + ie);
    S_s[o] = 0.5f * (e - ie);
  }
  // drain table loads/writes so they don't pollute the counted vmcnt pipeline
  MEMBAR();
  asm volatile("s_waitcnt vmcnt(0) lgkmcnt(0)" ::: "memory");
  __builtin_amdgcn_sched_barrier(0);

  // ---- per-thread staging sources (pre-swizzled: kc_logical = (tid&7) ^ (row&7)) ----
  const int kcl = (tid & 7) ^ ((tid >> 3) & 7);
  const unsigned short* wa[4];
#pragma unroll
  for (int j2 = 0; j2 < 4; ++j2) {
    int o = j2 * 64 + (tid >> 3);
    wa[j2] = Wt + o * KTOT + kcl * 8;
  }
  const unsigned short* ib[2];
#pragma unroll
  for (int j = 0; j < 2; ++j) {
    int ml = j * 64 + (tid >> 3);
    int oh = (ohw0 + ml) >> 5, ow = (ohw0 + ml) & 31;
    ib[j] = xp + ((b * HP + oh) * HP + ow) * 256 + kcl * 8;
  }

  // ---- per-lane fragment read offsets (swizzled) ----
  const int kq = lane >> 4, l15 = lane & 15;
  const int og = wid >> 1, mg = wid & 1;
  const int xa = l15 & 7;
  const int c0 = ((kq) ^ xa) * 16;
  const int c1 = ((4 + kq) ^ xa) * 16;
  const int ra = (og * 64 + l15) * 128;
  const int rb = (mg * 64 + l15) * 128;

  f32x4 acc[4][4];
#pragma unroll
  for (int i = 0; i < 4; ++i)
#pragma unroll
    for (int j = 0; j < 4; ++j) acc[i][j] = f32x4{0.f, 0.f, 0.f, 0.f};

  auto stage = [&](int t, int buf) {
    const int koff = t * 64;
    char* abase = smem + LDS_A_OFF + buf * 32768 + wid * 1024;
#pragma unroll
    for (int j2 = 0; j2 < 4; ++j2)
      gload16(wa[j2] + koff, abase + j2 * 8192);
    const int p = t >> 2;
    const int di = (p >= 6) ? 2 : ((p >= 3) ? 1 : 0);
    const int dj = p - di * 3;
    const int ioff = (di * HP + dj) * 256 + (t & 3) * 64;
    char* bbase = smem + LDS_B_OFF + buf * 16384 + wid * 1024;
    gload16(ib[0] + ioff, bbase);
    gload16(ib[1] + ioff, bbase + 8192);
  };

  // prologue: fill both ring slots
  stage(0, 0);
  stage(1, 1);

  for (int t = 0; t < 36; ++t) {
    const int buf = t & 1;
    // B1: tile t landed (counted: tile t+1's 6 loads may stay in flight)
    if (t < 35) asm volatile("s_waitcnt vmcnt(6)" ::: "memory");
    else        asm volatile("s_waitcnt vmcnt(0)" ::: "memory");
    RAWBAR();
    __builtin_amdgcn_sched_barrier(0);

    const char* Abuf = smem + LDS_A_OFF + buf * 32768;
    const char* Bbuf = smem + LDS_B_OFF + buf * 16384;
    bfx8 fa0[4], fa1[4], fb0[4], fb1[4];
#pragma unroll
    for (int oi = 0; oi < 4; ++oi) {
      fa0[oi] = *(const bfx8*)(Abuf + ra + oi * 2048 + c0);
      fa1[oi] = *(const bfx8*)(Abuf + ra + oi * 2048 + c1);
    }
#pragma unroll
    for (int mi = 0; mi < 4; ++mi) {
      fb0[mi] = *(const bfx8*)(Bbuf + rb + mi * 2048 + c0);
      fb1[mi] = *(const bfx8*)(Bbuf + rb + mi * 2048 + c1);
    }

    // k-step 0 MFMAs overlap the ks1 ds_reads still in flight
    __builtin_amdgcn_s_setprio(1);
#pragma unroll
    for (int oi = 0; oi < 4; ++oi)
#pragma unroll
      for (int mi = 0; mi < 4; ++mi)
        acc[oi][mi] = __builtin_amdgcn_mfma_f32_16x16x32_bf16(fa0[oi], fb0[mi], acc[oi][mi], 0, 0, 0);
    __builtin_amdgcn_s_setprio(0);

    // B2: all my LDS reads of buf complete before anyone overwrites it
    asm volatile("s_waitcnt lgkmcnt(0)" ::: "memory");
    __builtin_amdgcn_sched_barrier(0);
    RAWBAR();

    if (t < 34) stage(t + 2, buf);

    __builtin_amdgcn_s_setprio(1);
#pragma unroll
    for (int oi = 0; oi < 4; ++oi)
#pragma unroll
      for (int mi = 0; mi < 4; ++mi)
        acc[oi][mi] = __builtin_amdgcn_mfma_f32_16x16x32_bf16(fa1[oi], fb1[mi], acc[oi][mi], 0, 0, 0);
    __builtin_amdgcn_s_setprio(0);
  }

  // ---- epilogue: w = sinh(2 zn asinh(Am*dot*C - Bm*S)) ----
  const int o_base = og * 64, m_base = mg * 64;
#pragma unroll
  for (int oi = 0; oi < 4; ++oi) {
#pragma unroll
    for (int r = 0; r < 4; ++r) {
      int o = o_base + oi * 16 + kq * 4 + r;
      float zn2o = 2.f * zn_s[o], Co = C_s[o], So = S_s[o];
#pragma unroll
      for (int mi = 0; mi < 4; ++mi) {
        int mloc = m_base + mi * 16 + l15;
        float2 f = mf_s[mloc];
        float arg = f.x * acc[oi][mi][r] * Co - f.y * So;
        acc[oi][mi][r] = sinh_f(zn2o * asinh_f(arg));
      }
    }
  }

  // row sums of w^2 over o (4 o-groups x 64)
  float swp[4];
#pragma unroll
  for (int mi = 0; mi < 4; ++mi) {
    float s = 0.f;
#pragma unroll
    for (int oi = 0; oi < 4; ++oi)
#pragma unroll
      for (int r = 0; r < 4; ++r) s += acc[oi][mi][r] * acc[oi][mi][r];
    s += __shfl_xor(s, 16);
    s += __shfl_xor(s, 32);
    swp[mi] = s;
  }
  __syncthreads();   // also drains everything before table reuse
  if (lane < 16) {
#pragma unroll
    for (int mi = 0; mi < 4; ++mi) part_s[og][m_base + mi * 16 + lane] = swp[mi];
  }
  __syncthreads();

  float gm[4];
#pragma unroll
  for (int mi = 0; mi < 4; ++mi) {
    int mloc = m_base + mi * 16 + l15;
    float Sw = part_s[0][mloc] + part_s[1][mloc] + part_s[2][mloc] + part_s[3][mloc];
    float sq = sqrtf(fmaxf(Sw, 1e-30f));
    float s = 1.f / (1.f + sqrtf(1.f + Sw));
    float tt = fminf(s * sq, 1.f - 1e-7f);
    gm[mi] = atanh_f(tt) / sq;
  }

  float* outb = out + (b * 256) * 1024 + ohw0;
#pragma unroll
  for (int oi = 0; oi < 4; ++oi) {
#pragma unroll
    for (int r = 0; r < 4; ++r) {
      int o = o_base + oi * 16 + kq * 4 + r;
      float* op = outb + o * 1024;
#pragma unroll
      for (int mi = 0; mi < 4; ++mi)
        op[m_base + mi * 16 + l15] = acc[oi][mi][r] * gm[mi];
    }
  }
}

extern "C" void kernel_launch(void* const* d_in, const int* in_sizes, int n_in,
                              void* d_out, int out_size, void* d_ws, size_t ws_size,
                              hipStream_t stream) {
  const float* x    = (const float*)d_in[0];
  const float* wts  = (const float*)d_in[1];
  const float* bias = (const float*)d_in[2];
  float* out = (float*)d_out;
  char* ws = (char*)d_ws;
  unsigned short* xp = (unsigned short*)(ws + XP_OFF);
  unsigned short* Wt = (unsigned short*)(ws + WT_OFF);
  float* zn2 = (float*)(ws + ZN_OFF);
  float2* mfv = (float2*)(ws + MF_OFF);
  float* T = (float*)(ws + T_OFF);

  double bni = exp(::lgamma(128.0) + ::lgamma(0.5) - ::lgamma(128.5));
  double bn  = exp(::lgamma(1152.0) + ::lgamma(0.5) - ::lgamma(1152.5));
  float ratio = (float)(bn / bni);

  hipMemsetAsync(xp, 0, XP_BYTES, stream);
  k_prep_x<<<dim3(32, 32), 256, 0, stream>>>(x, xp, T, ratio);
  k_rowfac<<<128, 256, 0, stream>>>(T, mfv);
  k_zn<<<256, 256, 0, stream>>>(wts, zn2);
  k_wt<<<KTOT, 256, 0, stream>>>(wts, zn2, Wt);
  k_gemm<<<256, 512, LDS_TOTAL, stream>>>(xp, Wt, zn2, bias, mfv, out);
}